// Round 16
// baseline (1478.762 us; speedup 1.0000x reference)
//
#include <hip/hip_runtime.h>

typedef unsigned short u16;
typedef __bf16 bf16x8 __attribute__((ext_vector_type(8)));
typedef float f32x4 __attribute__((ext_vector_type(4)));

#define MFMA16(a,b,c) __builtin_amdgcn_mfma_f32_16x16x32_bf16(a,b,c,0,0,0)

// B=2048 S=64 E=256 D=512 IN=32 T=64 ; step-GEMM K = 32+512 = 544
#define NB 2048
#define NS 64
#define NE 256
#define ND 512
#define NT 64
#define KSTEP 544
#define SLAB (2048*544)
#define UW 288   // U row width (b-major layout)

__device__ __forceinline__ void ld16(void* lds, const void* g) {
  __builtin_amdgcn_global_load_lds(
      (__attribute__((address_space(1))) void*)(uintptr_t)g,
      (__attribute__((address_space(3))) void*)(unsigned int)(uintptr_t)lds,
      16, 0, 0);
}
__device__ __forceinline__ u16 f2bf(float f) {
  union { float f; unsigned u; } v; v.f = f;
  unsigned r = v.u + 0x7FFFu + ((v.u >> 16) & 1u);
  return (u16)(r >> 16);
}
__device__ __forceinline__ float bf2f(u16 h) {
  union { unsigned u; float f; } v; v.u = ((unsigned)h) << 16;
  return v.f;
}
__device__ __forceinline__ float sig(float x) { return 1.f / (1.f + __expf(-x)); }
__device__ __forceinline__ float tanh_(float x) {
  float ax = fabsf(x);
  float e = __expf(-2.f * ax);
  float r = (1.f - e) / (1.f + e);
  return copysignf(r, x);
}

// Stage a 128-row x 32-col (K) bf16 tile into 512 lane-linear 16B slots.
// Global chunk g = cslot ^ ((row>>1)&3): 4 adjacent lanes cover one contiguous
// 64B row segment (coalesced); frag reads land 2-way-per-bank (free).
__device__ __forceinline__ void stage128(u16* dst, const u16* src, int stride) {
  int tid = threadIdx.x;
  #pragma unroll
  for (int sweep = 0; sweep < 2; ++sweep) {
    int s = sweep * 256 + tid;
    int r = s >> 2;
    int g = (s & 3) ^ ((r >> 1) & 3);
    ld16(dst + (size_t)s * 8, src + (size_t)r * stride + g * 8);
  }
}

// One K=32 slice: 64x64 wave tile (mt=4 x nt=4), swizzled frag reads.
__device__ __forceinline__ void compute_tile(const u16* A, const u16* Bt,
                                             int w, int col, int quad,
                                             f32x4 (&acc)[4][4]) {
  int xs = quad ^ ((col >> 1) & 3);
  int ra = (w >> 1) * 64 + col;
  int rb = (w & 1) * 64 + col;
  bf16x8 a[4], b[4];
  #pragma unroll
  for (int mt = 0; mt < 4; ++mt)
    a[mt] = *(const bf16x8*)&A[(((ra + mt * 16) << 2) + xs) * 8];
  #pragma unroll
  for (int nt = 0; nt < 4; ++nt)
    b[nt] = *(const bf16x8*)&Bt[(((rb + nt * 16) << 2) + xs) * 8];
  #pragma unroll
  for (int mt = 0; mt < 4; ++mt)
    #pragma unroll
    for (int nt = 0; nt < 4; ++nt) acc[mt][nt] = MFMA16(a[mt], b[nt], acc[mt][nt]);
}

// ---------------- phase A ----------------

__global__ __launch_bounds__(256) void prep_enc(
    const float* __restrict__ cEnc, const float* __restrict__ Wfc,
    const float* __restrict__ hist, const float* __restrict__ cur,
    float* __restrict__ inp0, float* __restrict__ cw, u16* __restrict__ cEncB)
{
  __shared__ float meanP[4][256];
  int tid = threadIdx.x, lane = tid & 63, w = tid >> 6;
  int b = blockIdx.x;
  const float* base = cEnc + (size_t)b * NS * NE;
  float4 wf = *(const float4*)(Wfc + lane * 4);
  float m0 = 0, m1 = 0, m2 = 0, m3 = 0;
  for (int s = w * 16; s < w * 16 + 16; ++s) {
    float4 v = *(const float4*)(base + s * NE + lane * 4);
    m0 += v.x; m1 += v.y; m2 += v.z; m3 += v.w;
    ushort4 bv;
    bv.x = f2bf(v.x); bv.y = f2bf(v.y); bv.z = f2bf(v.z); bv.w = f2bf(v.w);
    *(ushort4*)(cEncB + (size_t)b * NS * NE + s * NE + lane * 4) = bv;
    float d = v.x * wf.x + v.y * wf.y + v.z * wf.z + v.w * wf.w;
    for (int off = 32; off; off >>= 1) d += __shfl_xor(d, off);
    if (lane == 0) cw[b * NS + s] = d;
  }
  meanP[w][lane*4+0] = m0; meanP[w][lane*4+1] = m1;
  meanP[w][lane*4+2] = m2; meanP[w][lane*4+3] = m3;
  __syncthreads();
  {
    float s = meanP[0][tid] + meanP[1][tid] + meanP[2][tid] + meanP[3][tid];
    inp0[(size_t)b * 288 + tid] = s * (1.f / 64.f);
  }
  if (tid < 32) {
    float x = (tid < 31) ? hist[b * 31 + tid] : cur[b * NT + 0];
    inp0[(size_t)b * 288 + 256 + tid] = x;
  }
}

__global__ void xfill(const float* __restrict__ hist, const float* __restrict__ cur,
                      u16* __restrict__ XH)
{
  int idx = blockIdx.x * 256 + threadIdx.x;   // 65*2048*32
  if (idx >= 65 * 2048 * 32) return;
  int k = idx & 31, b = (idx >> 5) & 2047, t = idx >> 16;
  float x = 0.f;
  if (t < 64) {
    int j = t + k - 31;
    x = (j >= 0) ? cur[b * NT + j] : hist[b * 31 + t + k];
  }
  XH[(size_t)(t * NB + b) * KSTEP + k] = f2bf(x);
}

// Wc3[dt][colB][k]: colB in [0,128): d = dt*32 + (colB>>6)*16 + (colB&15),
// gate = (colB>>4)&3, j = gate*512+d; k<32 -> W_ih else W_hh.
__global__ void cast_wc3(const float* __restrict__ Wih, const float* __restrict__ Whh,
                         u16* __restrict__ Wc3)
{
  int idx = blockIdx.x * 256 + threadIdx.x;   // 16*128*544
  if (idx >= 2048 * 544) return;
  int k = idx % 544;
  int rr = idx / 544;
  int colB = rr & 127, dt = rr >> 7;
  int d = dt * 32 + ((colB >> 6) << 4) + (colB & 15);
  int gate = (colB >> 4) & 3;
  int j = gate * 512 + d;
  float v = (k < 32) ? Wih[j * 32 + k] : Whh[j * 512 + (k - 32)];
  Wc3[idx] = f2bf(v);
}

__global__ void bsum_k(const float* __restrict__ bih, const float* __restrict__ bhh,
                       float* __restrict__ bsum)
{
  int i = blockIdx.x * 256 + threadIdx.x;
  if (i < 2048) bsum[i] = bih[i] + bhh[i];
}

// Wproj [896][512]: col<512 -> Wwp[col][k]; col-512=n<256 -> Wwa[k*256+n];
// n==256 -> bwa[k]; n==257 -> Wfc[256+k]; else 0.
__global__ void cast_wproj(const float* __restrict__ Wwp, const float* __restrict__ Wwa,
                           const float* __restrict__ bwa, const float* __restrict__ Wfc,
                           u16* __restrict__ O)
{
  int i = blockIdx.x * 256 + threadIdx.x;
  if (i >= 896 * 512) return;
  int c = i >> 9, k = i & 511;
  float v = 0.f;
  if (c < 512) v = Wwp[c * 512 + k];
  else {
    int n = c - 512;
    if (n < 256) v = Wwa[k * 256 + n];
    else if (n == 256) v = bwa[k];
    else if (n == 257) v = Wfc[256 + k];
  }
  O[i] = f2bf(v);
}

__global__ __launch_bounds__(256) void init_gemm(
    const float* __restrict__ inp0, const float* __restrict__ Wh, const float* __restrict__ Wc,
    const float* __restrict__ bh, const float* __restrict__ bc,
    u16* __restrict__ XH0, float* __restrict__ cbuf)
{
  __shared__ float As[64][33];
  __shared__ float Bs[64][33];
  int tid = threadIdx.x;
  int b0 = blockIdx.x * 64, n0 = blockIdx.y * 64;
  int tx = tid & 15, ty = tid >> 4;
  float acc[4][4] = {};
  for (int kk = 0; kk < 9; ++kk) {
    for (int sw = 0; sw < 2; ++sw) {
      int idx = sw * 256 + tid;
      int row = idx >> 3, c4 = idx & 7;
      float4 av = *(const float4*)(inp0 + (size_t)(b0 + row) * 288 + kk * 32 + c4 * 4);
      As[row][c4*4+0] = av.x; As[row][c4*4+1] = av.y; As[row][c4*4+2] = av.z; As[row][c4*4+3] = av.w;
      int n = n0 + row;
      const float* bs = (n < 512) ? (Wh + (size_t)n * 288) : (Wc + (size_t)(n - 512) * 288);
      float4 bv = *(const float4*)(bs + kk * 32 + c4 * 4);
      Bs[row][c4*4+0] = bv.x; Bs[row][c4*4+1] = bv.y; Bs[row][c4*4+2] = bv.z; Bs[row][c4*4+3] = bv.w;
    }
    __syncthreads();
    for (int k = 0; k < 32; ++k) {
      float a4[4], b4[4];
      #pragma unroll
      for (int i = 0; i < 4; ++i) a4[i] = As[ty * 4 + i][k];
      #pragma unroll
      for (int j = 0; j < 4; ++j) b4[j] = Bs[tx * 4 + j][k];
      #pragma unroll
      for (int i = 0; i < 4; ++i)
        #pragma unroll
        for (int j = 0; j < 4; ++j) acc[i][j] += a4[i] * b4[j];
    }
    __syncthreads();
  }
  for (int i = 0; i < 4; ++i)
    for (int j = 0; j < 4; ++j) {
      int b = b0 + ty * 4 + i, n = n0 + tx * 4 + j;
      float v = acc[i][j];
      if (n < 512) XH0[(size_t)b * KSTEP + 32 + n] = f2bf(v + bh[n]);
      else cbuf[(size_t)b * ND + n - 512] = v + bc[n - 512];
    }
}

// ---------------- phase B: fused LSTM, LDS-staged A (one drain/step) --------
// R15 showed the floor is LATENCY on cross-XCD h-reads (~900cy via L3/HBM;
// FETCH 83MB = h-reads from HBM) serialized by the 2-deep reg prefetch:
// 17 chunks x ~450cy ~= 15.5us/step. Fix: the block's ENTIRE A-tile
// (128x544x2B = 139KB) fits LDS -> post-gate, issue ALL 17 stage128 calls
// (34 independent global_load_lds/thread, no waits between), then ONE
// __syncthreads() drain. Latency paid once across 34 in-flight loads ->
// bandwidth-bound. K-loop reads A from LDS (verified swizzle), B 2-deep from
// L2 regs. Gate: per-dt RELEASE-STORE flags (no atomic RMW serialization);
// consumer lanes 0..15 poll one flag each, relaxed (no INV -> weights and
// stale-free handoff preserved; all slab-t reads post-gate).
__global__ __launch_bounds__(256, 1) void lstm_fused(
    u16* __restrict__ XH, const u16* __restrict__ Wc3,
    const float* __restrict__ bsum, const float* __restrict__ cbuf,
    int* __restrict__ flags)
{
  extern __shared__ __align__(16) u16 As[];   // 17 * 4096 u16 = 139264 B
  int tid = threadIdx.x, lane = tid & 63, w = tid >> 6;
  int col = lane & 15, quad = lane >> 4;
  int bx = blockIdx.x, dt = blockIdx.y;
  int b0 = bx * 128;
  int d = dt * 32 + (w & 1) * 16 + col;
  int xs = quad ^ ((col >> 1) & 3);
  int ra = (w >> 1) * 64 + col;

  size_t boff[4];
  #pragma unroll
  for (int nt = 0; nt < 4; ++nt)
    boff[nt] = (size_t)(dt * 128 + (w & 1) * 64 + nt * 16 + col) * KSTEP + quad * 8;

  // c-state in registers (cbuf is read-only from here on).
  float cst[4][4];
  int row0 = b0 + (w >> 1) * 64 + quad * 4;
  #pragma unroll
  for (int mt = 0; mt < 4; ++mt)
    #pragma unroll
    for (int r = 0; r < 4; ++r)
      cst[mt][r] = cbuf[(size_t)(row0 + mt * 16 + r) * ND + d];
  float bi = bsum[d], bf_ = bsum[512 + d], bg = bsum[1024 + d], bo = bsum[1536 + d];

#define LDSA(DST, KK) do {                                          \
    const u16* A_ = As + (KK) * 4096;                               \
    _Pragma("unroll")                                               \
    for (int mt = 0; mt < 4; ++mt)                                  \
      DST[mt] = *(const bf16x8*)&A_[(((ra + mt * 16) << 2) + xs) * 8]; \
  } while (0)
#define LOAD_B(DST, KK) do {                                        \
    _Pragma("unroll")                                               \
    for (int nt = 0; nt < 4; ++nt)                                  \
      DST[nt] = *(const bf16x8*)(Wc3 + boff[nt] + (KK) * 32);       \
  } while (0)
#define MFMA_BLK(A4, B4) do {                                       \
    _Pragma("unroll")                                               \
    for (int mt = 0; mt < 4; ++mt)                                  \
      _Pragma("unroll")                                             \
      for (int nt = 0; nt < 4; ++nt)                                \
        acc[mt][nt] = MFMA16(A4[mt], B4[nt], acc[mt][nt]);          \
  } while (0)

  for (int t = 0; t < 64; ++t) {
    const u16* Abase = XH + (size_t)t * SLAB + (size_t)b0 * KSTEP;
    bf16x8 aC[4], aN[4], bC[4], bN[4];
    LOAD_B(bC, 0); LOAD_B(bN, 1);   // weights only (L2-hit): safe pre-gate
    if (t > 0) {
      if (tid < 16) {
        // Relaxed poll on this group's 16 per-dt flags (one lane each);
        // no buffer_inv -> L2-resident weights retained.
        const int* f = flags + ((size_t)(t - 1) * 16 + bx) * 16 + tid;
        while (__hip_atomic_load(f, __ATOMIC_RELAXED,
                                 __HIP_MEMORY_SCOPE_AGENT) == 0) {
          __builtin_amdgcn_s_sleep(2);
        }
      }
      __syncthreads();   // all lanes' slab-t reads ordered after poll exit
    }
    // Stage the ENTIRE A-tile: 34 independent global_load_lds per thread.
    #pragma unroll
    for (int kk = 0; kk < 17; ++kk)
      stage128(As + kk * 4096, Abase + kk * 32, KSTEP);
    __syncthreads();   // ONE vmcnt drain for all 17 chunks

    f32x4 acc[4][4] = {};
    #pragma unroll
    for (int j = 0; j < 8; ++j) {          // kk = 2j, 2j+1
      LDSA(aC, 2 * j);     MFMA_BLK(aC, bC); LOAD_B(bC, 2 * j + 2);
      LDSA(aN, 2 * j + 1); MFMA_BLK(aN, bN);
      if (j < 7) LOAD_B(bN, 2 * j + 3);
    }
    LDSA(aC, 16); MFMA_BLK(aC, bC);        // kk = 16

    // Elementwise LSTM tail (verified lstm_step2 mapping); h -> XH[t+1]
    // via NORMAL stores (dirty in producer L2; wbl2 at release -> L3 fresh).
    u16* Hn = XH + (size_t)(t + 1) * SLAB;
    #pragma unroll
    for (int mt = 0; mt < 4; ++mt)
      #pragma unroll
      for (int r = 0; r < 4; ++r) {
        int row = row0 + mt * 16 + r;
        float gi = acc[mt][0][r] + bi;
        float gf = acc[mt][1][r] + bf_;
        float gg = acc[mt][2][r] + bg;
        float go = acc[mt][3][r] + bo;
        float c2 = sig(gf) * cst[mt][r] + sig(gi) * tanh_(gg);
        cst[mt][r] = c2;
        Hn[(size_t)row * KSTEP + 32 + d] = f2bf(sig(go) * tanh_(c2));
      }
    // Barrier drains all waves' h-stores; tid0's RELEASE store then emits
    // wbl2 (h -> L3, cross-XCD visible) and publishes this block's flag.
    __syncthreads();
    if (tid == 0)
      __hip_atomic_store(flags + ((size_t)t * 16 + bx) * 16 + dt, 1,
                         __ATOMIC_RELEASE, __HIP_MEMORY_SCOPE_AGENT);
  }
#undef LDSA
#undef LOAD_B
#undef MFMA_BLK
}

// ---------------- phase C: merged projection GEMM ----------------
// rows = 131072 (t*NB+b), cols = 896 packed [Wwp 512 | Wu 288 | pad].
// ct<4: tanh(+bwp)*vp row-reduction -> atomicAdd partials.
// ct>=4: U write, b-major UT[b][t][uc], uc<288.
__global__ __launch_bounds__(256) void proj_gemm(
    const u16* __restrict__ H, const u16* __restrict__ Wp,
    const float* __restrict__ bwp, const float* __restrict__ vp,
    float* __restrict__ apart, u16* __restrict__ UT)
{
  __shared__ __align__(16) u16 As[3][4096];
  __shared__ __align__(16) u16 Bs[3][4096];
  int tid = threadIdx.x, lane = tid & 63, w = tid >> 6;
  int col = lane & 15, quad = lane >> 4;
  size_t r0 = (size_t)blockIdx.y * 128;
  int ct = blockIdx.x;
  const u16* Abase = H + r0 * KSTEP;
  const u16* Bbase = Wp + (size_t)ct * 128 * 512;
  f32x4 acc[4][4] = {};
  stage128(As[0], Abase, KSTEP);      stage128(Bs[0], Bbase, 512);
  stage128(As[1], Abase + 32, KSTEP); stage128(Bs[1], Bbase + 32, 512);
  for (int kk = 0; kk < 16; ++kk) {
    __syncthreads();
    if (kk + 2 < 16) {
      int m = (kk + 2) % 3;
      stage128(As[m], Abase + (kk + 2) * 32, KSTEP);
      stage128(Bs[m], Bbase + (kk + 2) * 32, 512);
    }
    compute_tile(As[kk % 3], Bs[kk % 3], w, col, quad, acc);
  }
  if (ct < 4) {
    float part[4][4] = {};
    #pragma unroll
    for (int nt = 0; nt < 4; ++nt) {
      int oc = ct * 128 + (w & 1) * 64 + nt * 16 + col;
      float bw = bwp[oc], vv = vp[oc];
      #pragma unroll
      for (int mt = 0; mt < 4; ++mt)
        #pragma unroll
        for (int r = 0; r < 4; ++r) part[mt][r] += tanh_(acc[mt][nt][r] + bw) * vv;
    }
    #pragma unroll
    for (int mt = 0; mt < 4; ++mt)
      #pragma unroll
      for (int r = 0; r < 4; ++r) {
        float p = part[mt][r];
        p += __shfl_xor(p, 1); p += __shfl_xor(p, 2);
        p += __shfl_xor(p, 4); p += __shfl_xor(p, 8);
        if (col == 0)
          atomicAdd(&apart[r0 + (w >> 1) * 64 + mt * 16 + quad * 4 + r], p);
      }
  } else {
    #pragma unroll
    for (int nt = 0; nt < 4; ++nt) {
      int uc = (ct - 4) * 128 + (w & 1) * 64 + nt * 16 + col;
      if (uc < UW) {
        #pragma unroll
        for (int mt = 0; mt < 4; ++mt)
          #pragma unroll
          for (int r = 0; r < 4; ++r) {
            size_t row = r0 + (w >> 1) * 64 + mt * 16 + quad * 4 + r;
            int t = (int)(row >> 11), b = (int)(row & 2047);
            UT[((size_t)b * NT + t) * UW + uc] = f2bf(acc[mt][nt][r]);
          }
      }
    }
  }
}

__global__ void finish_aligned(const float* __restrict__ apart,
                               const float* __restrict__ bvp,
                               float* __restrict__ alg)
{
  int i = blockIdx.x * 256 + threadIdx.x;
  if (i < 131072) alg[i] = 64.f * sig(apart[i] + bvp[0]);
}

// ---------------- attention ----------------
__global__ __launch_bounds__(256) void attn_kernel(
    const u16* __restrict__ cEncB, const u16* __restrict__ UT,
    const float* __restrict__ alignedIn, const float* __restrict__ cw,
    const float* __restrict__ bfc,
    float* __restrict__ preds, float* __restrict__ alphas)
{
  __shared__ __align__(16) u16 Ae[64 * 256];
  __shared__ __align__(16) u16 Ue[64 * 256];
  __shared__ float attL[64 * 68];
  __shared__ float s0L[64], hwL[64], alL[64], cwL[64], mL[64], zL[64];
  __shared__ float red[4][64];
  int tid = threadIdx.x, lane = tid & 63, w = tid >> 6;
  int col = lane & 15, quad = lane >> 4;
  int b = blockIdx.x;
  const u16* eb = cEncB + (size_t)b * NS * NE;
  const u16* ub = UT + (size_t)b * NT * UW;
  // stage: 2048 slots each; slot idx holds row r = idx>>5, global chunk g = (idx&31)^(r&7)
  for (int sw = 0; sw < 8; ++sw) {
    int idx = sw * 256 + tid;
    int r = idx >> 5, cs = idx & 31, g = cs ^ (r & 7);
    ld16(&Ae[idx * 8], eb + (size_t)r * NE + g * 8);
    ld16(&Ue[idx * 8], ub + (size_t)r * UW + g * 8);
  }
  if (tid < 64) {
    s0L[tid] = bf2f(ub[tid * UW + 256]);
    hwL[tid] = bf2f(ub[tid * UW + 257]);
    alL[tid] = alignedIn[(size_t)tid * NB + b];
    cwL[tid] = cw[b * NS + tid];
  }
  __syncthreads();
  f32x4 acc[4] = {};
  int rowA = w * 16 + col;
  #pragma unroll
  for (int kk = 0; kk < 8; ++kk) {
    int ga = (kk * 4 + quad);
    bf16x8 a = *(const bf16x8*)&Ae[(rowA * 32 + (ga ^ (rowA & 7))) * 8];
    #pragma unroll
    for (int nt = 0; nt < 4; ++nt) {
      int rowB = nt * 16 + col;
      bf16x8 bb = *(const bf16x8*)&Ue[(rowB * 32 + (ga ^ (rowB & 7))) * 8];
      acc[nt] = MFMA16(a, bb, acc[nt]);
    }
  }
  for (int nt = 0; nt < 4; ++nt) {
    int t = nt * 16 + col;
    #pragma unroll
    for (int r = 0; r < 4; ++r) {
      int s = w * 16 + quad * 4 + r;
      attL[s * 68 + t] = acc[nt][r] + s0L[t];
    }
  }
  __syncthreads();
  int t = tid & 63, qq = tid >> 6;
  float pm = -1e30f;
  for (int s = qq * 16; s < qq * 16 + 16; ++s) pm = fmaxf(pm, attL[s * 68 + t]);
  red[qq][t] = pm;
  __syncthreads();
  if (tid < 64)
    mL[tid] = fmaxf(fmaxf(red[0][tid], red[1][tid]), fmaxf(red[2][tid], red[3][tid]));
  __syncthreads();
  float m = mL[t];
  float ps = 0.f;
  for (int s = qq * 16; s < qq * 16 + 16; ++s) ps += __expf(attL[s * 68 + t] - m);
  red[qq][t] = ps;
  __syncthreads();
  if (tid < 64) zL[tid] = red[0][tid] + red[1][tid] + red[2][tid] + red[3][tid];
  __syncthreads();
  float zinv = 1.f / zL[t];
  float al = alL[t];
  float pp = 0.f;
  float* aout = alphas + (size_t)b * (NT * NS) + t * NS;
  for (int s = qq * 16; s < qq * 16 + 16; ++s) {
    float e = __expf(attL[s * 68 + t] - m) * zinv;
    float ds = (float)s - al;
    float a = e * __expf(-0.5f * ds * ds);
    aout[s] = a;
    pp += a * cwL[s];
  }
  red[qq][t] = pp;
  __syncthreads();
  if (tid < 64)
    preds[(size_t)b * NT + tid] =
        red[0][tid] + red[1][tid] + red[2][tid] + red[3][tid] + hwL[tid] + bfc[0];
}

extern "C" void kernel_launch(void* const* d_in, const int* in_sizes, int n_in,
                              void* d_out, int out_size, void* d_ws, size_t ws_size,
                              hipStream_t stream) {
  const float* cEnc = (const float*)d_in[0];
  const float* cur  = (const float*)d_in[1];
  const float* hist = (const float*)d_in[2];
  const float* WIh  = (const float*)d_in[6];
  const float* bIh  = (const float*)d_in[7];
  const float* WIc  = (const float*)d_in[8];
  const float* bIc  = (const float*)d_in[9];
  const float* Wih  = (const float*)d_in[10];
  const float* Whh  = (const float*)d_in[11];
  const float* bih  = (const float*)d_in[12];
  const float* bhh  = (const float*)d_in[13];
  const float* Wwa  = (const float*)d_in[14];
  const float* bwa  = (const float*)d_in[15];
  const float* Wwp  = (const float*)d_in[16];
  const float* bwp  = (const float*)d_in[17];
  const float* Wvp  = (const float*)d_in[18];
  const float* bvp  = (const float*)d_in[19];
  const float* Wfc  = (const float*)d_in[20];
  const float* bfc  = (const float*)d_in[21];
  float* preds  = (float*)d_out;
  float* alphas = preds + (size_t)NB * NT;

  char* ws = (char*)d_ws;
  size_t off = 0;
  auto alloc = [&](size_t bytes) { void* p = ws + off; off += (bytes + 255) & ~(size_t)255; return p; };
  u16*   XH    = (u16*)  alloc((size_t)65 * SLAB * 2);
  u16*   UT    = (u16*)  alloc((size_t)NB * NT * UW * 2);
  u16*   cEncB = (u16*)  alloc((size_t)NB * NS * NE * 2);
  float* cbuf  = (float*)alloc((size_t)NB * ND * 4);
  float* inp0  = (float*)alloc((size_t)NB * 288 * 4);
  float* cwb   = (float*)alloc((size_t)NB * NS * 4);
  float* alg   = (float*)alloc((size_t)131072 * 4);
  float* apart = (float*)alloc((size_t)131072 * 4);
  u16*   Wc3   = (u16*)  alloc((size_t)2048 * 544 * 2);
  u16*   Wproj = (u16*)  alloc((size_t)896 * 512 * 2);
  float* bsum  = (float*)alloc((size_t)2048 * 4);
  int*   flags = (int*)  alloc((size_t)64 * 16 * 16 * 4);

  static bool lds_attr_set = false;
  if (!lds_attr_set) {
    (void)hipFuncSetAttribute((const void*)lstm_fused,
                              hipFuncAttributeMaxDynamicSharedMemorySize, 139264);
    lds_attr_set = true;
  }

  prep_enc<<<NB, 256, 0, stream>>>(cEnc, Wfc, hist, cur, inp0, cwb, cEncB);
  xfill<<<16640, 256, 0, stream>>>(hist, cur, XH);
  cast_wc3<<<4352, 256, 0, stream>>>(Wih, Whh, Wc3);
  bsum_k<<<8, 256, 0, stream>>>(bih, bhh, bsum);
  cast_wproj<<<1792, 256, 0, stream>>>(Wwp, Wwa, bwa, Wfc, Wproj);
  init_gemm<<<dim3(32, 16), 256, 0, stream>>>(inp0, WIh, WIc, bIh, bIc, XH, cbuf);
  hipMemsetAsync(apart, 0, (size_t)131072 * 4, stream);
  hipMemsetAsync(flags, 0, (size_t)64 * 16 * 16 * 4, stream);
  lstm_fused<<<dim3(16, 16), 256, 139264, stream>>>(XH, Wc3, bsum, cbuf, flags);
  const u16* H = XH + (size_t)SLAB + 32;
  proj_gemm<<<dim3(7, 1024), 256, 0, stream>>>(H, Wproj, bwp, Wvp, apart, UT);
  finish_aligned<<<512, 256, 0, stream>>>(apart, bvp, alg);
  attn_kernel<<<NB, 256, 0, stream>>>(cEncB, UT, alg, cwb, bfc, preds, alphas);
}

// Round 17
// 1163.223 us; speedup vs baseline: 1.2713x; 1.2713x over previous
//
#include <hip/hip_runtime.h>

typedef unsigned short u16;
typedef __bf16 bf16x8 __attribute__((ext_vector_type(8)));
typedef float f32x4 __attribute__((ext_vector_type(4)));

#define MFMA16(a,b,c) __builtin_amdgcn_mfma_f32_16x16x32_bf16(a,b,c,0,0,0)

// B=2048 S=64 E=256 D=512 IN=32 T=64 ; step-GEMM K = 32+512 = 544
#define NB 2048
#define NS 64
#define NE 256
#define ND 512
#define NT 64
#define KSTEP 544
#define SLAB (2048*544)
#define UW 288   // U row width (b-major layout)

__device__ __forceinline__ void ld16(void* lds, const void* g) {
  __builtin_amdgcn_global_load_lds(
      (__attribute__((address_space(1))) void*)(uintptr_t)g,
      (__attribute__((address_space(3))) void*)(unsigned int)(uintptr_t)lds,
      16, 0, 0);
}
__device__ __forceinline__ u16 f2bf(float f) {
  union { float f; unsigned u; } v; v.f = f;
  unsigned r = v.u + 0x7FFFu + ((v.u >> 16) & 1u);
  return (u16)(r >> 16);
}
__device__ __forceinline__ float bf2f(u16 h) {
  union { unsigned u; float f; } v; v.u = ((unsigned)h) << 16;
  return v.f;
}
__device__ __forceinline__ float sig(float x) { return 1.f / (1.f + __expf(-x)); }
__device__ __forceinline__ float tanh_(float x) {
  float ax = fabsf(x);
  float e = __expf(-2.f * ax);
  float r = (1.f - e) / (1.f + e);
  return copysignf(r, x);
}

// Stage a 128-row x 32-col (K) bf16 tile into 512 lane-linear 16B slots.
// Global chunk g = cslot ^ ((row>>1)&3): 4 adjacent lanes cover one contiguous
// 64B row segment (coalesced); frag reads land 2-way-per-bank (free).
__device__ __forceinline__ void stage128(u16* dst, const u16* src, int stride) {
  int tid = threadIdx.x;
  #pragma unroll
  for (int sweep = 0; sweep < 2; ++sweep) {
    int s = sweep * 256 + tid;
    int r = s >> 2;
    int g = (s & 3) ^ ((r >> 1) & 3);
    ld16(dst + (size_t)s * 8, src + (size_t)r * stride + g * 8);
  }
}

// One K=32 slice: 64x64 wave tile (mt=4 x nt=4), swizzled frag reads.
__device__ __forceinline__ void compute_tile(const u16* A, const u16* Bt,
                                             int w, int col, int quad,
                                             f32x4 (&acc)[4][4]) {
  int xs = quad ^ ((col >> 1) & 3);
  int ra = (w >> 1) * 64 + col;
  int rb = (w & 1) * 64 + col;
  bf16x8 a[4], b[4];
  #pragma unroll
  for (int mt = 0; mt < 4; ++mt)
    a[mt] = *(const bf16x8*)&A[(((ra + mt * 16) << 2) + xs) * 8];
  #pragma unroll
  for (int nt = 0; nt < 4; ++nt)
    b[nt] = *(const bf16x8*)&Bt[(((rb + nt * 16) << 2) + xs) * 8];
  #pragma unroll
  for (int mt = 0; mt < 4; ++mt)
    #pragma unroll
    for (int nt = 0; nt < 4; ++nt) acc[mt][nt] = MFMA16(a[mt], b[nt], acc[mt][nt]);
}

// ---------------- phase A ----------------

__global__ __launch_bounds__(256) void prep_enc(
    const float* __restrict__ cEnc, const float* __restrict__ Wfc,
    const float* __restrict__ hist, const float* __restrict__ cur,
    float* __restrict__ inp0, float* __restrict__ cw, u16* __restrict__ cEncB)
{
  __shared__ float meanP[4][256];
  int tid = threadIdx.x, lane = tid & 63, w = tid >> 6;
  int b = blockIdx.x;
  const float* base = cEnc + (size_t)b * NS * NE;
  float4 wf = *(const float4*)(Wfc + lane * 4);
  float m0 = 0, m1 = 0, m2 = 0, m3 = 0;
  for (int s = w * 16; s < w * 16 + 16; ++s) {
    float4 v = *(const float4*)(base + s * NE + lane * 4);
    m0 += v.x; m1 += v.y; m2 += v.z; m3 += v.w;
    ushort4 bv;
    bv.x = f2bf(v.x); bv.y = f2bf(v.y); bv.z = f2bf(v.z); bv.w = f2bf(v.w);
    *(ushort4*)(cEncB + (size_t)b * NS * NE + s * NE + lane * 4) = bv;
    float d = v.x * wf.x + v.y * wf.y + v.z * wf.z + v.w * wf.w;
    for (int off = 32; off; off >>= 1) d += __shfl_xor(d, off);
    if (lane == 0) cw[b * NS + s] = d;
  }
  meanP[w][lane*4+0] = m0; meanP[w][lane*4+1] = m1;
  meanP[w][lane*4+2] = m2; meanP[w][lane*4+3] = m3;
  __syncthreads();
  {
    float s = meanP[0][tid] + meanP[1][tid] + meanP[2][tid] + meanP[3][tid];
    inp0[(size_t)b * 288 + tid] = s * (1.f / 64.f);
  }
  if (tid < 32) {
    float x = (tid < 31) ? hist[b * 31 + tid] : cur[b * NT + 0];
    inp0[(size_t)b * 288 + 256 + tid] = x;
  }
}

__global__ void xfill(const float* __restrict__ hist, const float* __restrict__ cur,
                      u16* __restrict__ XH)
{
  int idx = blockIdx.x * 256 + threadIdx.x;   // 65*2048*32
  if (idx >= 65 * 2048 * 32) return;
  int k = idx & 31, b = (idx >> 5) & 2047, t = idx >> 16;
  float x = 0.f;
  if (t < 64) {
    int j = t + k - 31;
    x = (j >= 0) ? cur[b * NT + j] : hist[b * 31 + t + k];
  }
  XH[(size_t)(t * NB + b) * KSTEP + k] = f2bf(x);
}

// Wc3[dt][colB][k]: colB in [0,128): d = dt*32 + (colB>>6)*16 + (colB&15),
// gate = (colB>>4)&3, j = gate*512+d; k<32 -> W_ih else W_hh.
__global__ void cast_wc3(const float* __restrict__ Wih, const float* __restrict__ Whh,
                         u16* __restrict__ Wc3)
{
  int idx = blockIdx.x * 256 + threadIdx.x;   // 16*128*544
  if (idx >= 2048 * 544) return;
  int k = idx % 544;
  int rr = idx / 544;
  int colB = rr & 127, dt = rr >> 7;
  int d = dt * 32 + ((colB >> 6) << 4) + (colB & 15);
  int gate = (colB >> 4) & 3;
  int j = gate * 512 + d;
  float v = (k < 32) ? Wih[j * 32 + k] : Whh[j * 512 + (k - 32)];
  Wc3[idx] = f2bf(v);
}

__global__ void bsum_k(const float* __restrict__ bih, const float* __restrict__ bhh,
                       float* __restrict__ bsum)
{
  int i = blockIdx.x * 256 + threadIdx.x;
  if (i < 2048) bsum[i] = bih[i] + bhh[i];
}

// Wproj [896][512]: col<512 -> Wwp[col][k]; col-512=n<256 -> Wwa[k*256+n];
// n==256 -> bwa[k]; n==257 -> Wfc[256+k]; else 0.
__global__ void cast_wproj(const float* __restrict__ Wwp, const float* __restrict__ Wwa,
                           const float* __restrict__ bwa, const float* __restrict__ Wfc,
                           u16* __restrict__ O)
{
  int i = blockIdx.x * 256 + threadIdx.x;
  if (i >= 896 * 512) return;
  int c = i >> 9, k = i & 511;
  float v = 0.f;
  if (c < 512) v = Wwp[c * 512 + k];
  else {
    int n = c - 512;
    if (n < 256) v = Wwa[k * 256 + n];
    else if (n == 256) v = bwa[k];
    else if (n == 257) v = Wfc[256 + k];
  }
  O[i] = f2bf(v);
}

__global__ __launch_bounds__(256) void init_gemm(
    const float* __restrict__ inp0, const float* __restrict__ Wh, const float* __restrict__ Wc,
    const float* __restrict__ bh, const float* __restrict__ bc,
    u16* __restrict__ XH0, float* __restrict__ cbuf)
{
  __shared__ float As[64][33];
  __shared__ float Bs[64][33];
  int tid = threadIdx.x;
  int b0 = blockIdx.x * 64, n0 = blockIdx.y * 64;
  int tx = tid & 15, ty = tid >> 4;
  float acc[4][4] = {};
  for (int kk = 0; kk < 9; ++kk) {
    for (int sw = 0; sw < 2; ++sw) {
      int idx = sw * 256 + tid;
      int row = idx >> 3, c4 = idx & 7;
      float4 av = *(const float4*)(inp0 + (size_t)(b0 + row) * 288 + kk * 32 + c4 * 4);
      As[row][c4*4+0] = av.x; As[row][c4*4+1] = av.y; As[row][c4*4+2] = av.z; As[row][c4*4+3] = av.w;
      int n = n0 + row;
      const float* bs = (n < 512) ? (Wh + (size_t)n * 288) : (Wc + (size_t)(n - 512) * 288);
      float4 bv = *(const float4*)(bs + kk * 32 + c4 * 4);
      Bs[row][c4*4+0] = bv.x; Bs[row][c4*4+1] = bv.y; Bs[row][c4*4+2] = bv.z; Bs[row][c4*4+3] = bv.w;
    }
    __syncthreads();
    for (int k = 0; k < 32; ++k) {
      float a4[4], b4[4];
      #pragma unroll
      for (int i = 0; i < 4; ++i) a4[i] = As[ty * 4 + i][k];
      #pragma unroll
      for (int j = 0; j < 4; ++j) b4[j] = Bs[tx * 4 + j][k];
      #pragma unroll
      for (int i = 0; i < 4; ++i)
        #pragma unroll
        for (int j = 0; j < 4; ++j) acc[i][j] += a4[i] * b4[j];
    }
    __syncthreads();
  }
  for (int i = 0; i < 4; ++i)
    for (int j = 0; j < 4; ++j) {
      int b = b0 + ty * 4 + i, n = n0 + tx * 4 + j;
      float v = acc[i][j];
      if (n < 512) XH0[(size_t)b * KSTEP + 32 + n] = f2bf(v + bh[n]);
      else cbuf[(size_t)b * ND + n - 512] = v + bc[n - 512];
    }
}

// ---------------- phase B: fused LSTM, write-through handoff, ZERO cache ops -
// R16 (LDS-staged A, one drain) matched R15 -> the ~11us/step mystery cost is
// NOT load latency. Remaining per-step cache op: the producer RELEASE's
// buffer_wbl2 = full L2 dirty-tag walk, 32 blocks/XCD/step, partially
// serialized -> O(10us). Present in EVERY prior variant (incl. per-launch
// boundary flush) -> explains the invariant 12-19us floor.
// This version has NO release, NO wbl2, NO inv:
//  - h-stores are agent-scope RELAXED ATOMIC stores (sc1: bypass L2, commit
//    at L3 coherent point; no dirty lines anywhere);
//  - __syncthreads() drains vmcnt (h committed at L3);
//  - flag publish is a RELAXED atomic store (ordered behind h by the drain);
//  - consumer polls flags with RELAXED atomic loads (sc1, prompt), then
//    stages A with normal loads (no stale copy can exist: h never entered
//    any L2; slab t never read before step t). Weights stay L2-resident.
__global__ __launch_bounds__(256, 1) void lstm_fused(
    u16* __restrict__ XH, const u16* __restrict__ Wc3,
    const float* __restrict__ bsum, const float* __restrict__ cbuf,
    int* __restrict__ flags)
{
  extern __shared__ __align__(16) u16 As[];   // 17 * 4096 u16 = 139264 B
  int tid = threadIdx.x, lane = tid & 63, w = tid >> 6;
  int col = lane & 15, quad = lane >> 4;
  int bx = blockIdx.x, dt = blockIdx.y;
  int b0 = bx * 128;
  int d = dt * 32 + (w & 1) * 16 + col;
  int xs = quad ^ ((col >> 1) & 3);
  int ra = (w >> 1) * 64 + col;

  size_t boff[4];
  #pragma unroll
  for (int nt = 0; nt < 4; ++nt)
    boff[nt] = (size_t)(dt * 128 + (w & 1) * 64 + nt * 16 + col) * KSTEP + quad * 8;

  // c-state in registers (cbuf is read-only from here on).
  float cst[4][4];
  int row0 = b0 + (w >> 1) * 64 + quad * 4;
  #pragma unroll
  for (int mt = 0; mt < 4; ++mt)
    #pragma unroll
    for (int r = 0; r < 4; ++r)
      cst[mt][r] = cbuf[(size_t)(row0 + mt * 16 + r) * ND + d];
  float bi = bsum[d], bf_ = bsum[512 + d], bg = bsum[1024 + d], bo = bsum[1536 + d];

#define LDSA(DST, KK) do {                                          \
    const u16* A_ = As + (KK) * 4096;                               \
    _Pragma("unroll")                                               \
    for (int mt = 0; mt < 4; ++mt)                                  \
      DST[mt] = *(const bf16x8*)&A_[(((ra + mt * 16) << 2) + xs) * 8]; \
  } while (0)
#define LOAD_B(DST, KK) do {                                        \
    _Pragma("unroll")                                               \
    for (int nt = 0; nt < 4; ++nt)                                  \
      DST[nt] = *(const bf16x8*)(Wc3 + boff[nt] + (KK) * 32);       \
  } while (0)
#define MFMA_BLK(A4, B4) do {                                       \
    _Pragma("unroll")                                               \
    for (int mt = 0; mt < 4; ++mt)                                  \
      _Pragma("unroll")                                             \
      for (int nt = 0; nt < 4; ++nt)                                \
        acc[mt][nt] = MFMA16(A4[mt], B4[nt], acc[mt][nt]);          \
  } while (0)

  for (int t = 0; t < 64; ++t) {
    const u16* Abase = XH + (size_t)t * SLAB + (size_t)b0 * KSTEP;
    bf16x8 aC[4], aN[4], bC[4], bN[4];
    LOAD_B(bC, 0); LOAD_B(bN, 1);   // weights only (L2-hit): safe pre-gate
    if (t > 0) {
      if (tid < 16) {
        // Relaxed atomic poll (sc1: reads L3 directly, no INV emitted).
        const int* f = flags + ((size_t)(t - 1) * 16 + bx) * 16 + tid;
        while (__hip_atomic_load(f, __ATOMIC_RELAXED,
                                 __HIP_MEMORY_SCOPE_AGENT) == 0) {
          __builtin_amdgcn_s_sleep(2);
        }
      }
      __syncthreads();   // all lanes' slab-t reads ordered after poll exit
    }
    // Stage the ENTIRE A-tile: 34 independent global_load_lds per thread.
    #pragma unroll
    for (int kk = 0; kk < 17; ++kk)
      stage128(As + kk * 4096, Abase + kk * 32, KSTEP);
    __syncthreads();   // ONE vmcnt drain for all 17 chunks

    f32x4 acc[4][4] = {};
    #pragma unroll
    for (int j = 0; j < 8; ++j) {          // kk = 2j, 2j+1
      LDSA(aC, 2 * j);     MFMA_BLK(aC, bC); LOAD_B(bC, 2 * j + 2);
      LDSA(aN, 2 * j + 1); MFMA_BLK(aN, bN);
      if (j < 7) LOAD_B(bN, 2 * j + 3);
    }
    LDSA(aC, 16); MFMA_BLK(aC, bC);        // kk = 16

    // Elementwise LSTM tail (verified lstm_step2 mapping); h -> XH[t+1]
    // via WRITE-THROUGH (agent relaxed atomic = sc1, commits at L3,
    // no dirty L2 lines -> no wbl2 needed ever).
    u16* Hn = XH + (size_t)(t + 1) * SLAB;
    #pragma unroll
    for (int mt = 0; mt < 4; ++mt)
      #pragma unroll
      for (int r = 0; r < 4; ++r) {
        int row = row0 + mt * 16 + r;
        float gi = acc[mt][0][r] + bi;
        float gf = acc[mt][1][r] + bf_;
        float gg = acc[mt][2][r] + bg;
        float go = acc[mt][3][r] + bo;
        float c2 = sig(gf) * cst[mt][r] + sig(gi) * tanh_(gg);
        cst[mt][r] = c2;
        __hip_atomic_store(&Hn[(size_t)row * KSTEP + 32 + d],
                           f2bf(sig(go) * tanh_(c2)),
                           __ATOMIC_RELAXED, __HIP_MEMORY_SCOPE_AGENT);
      }
    // Barrier drains vmcnt (h committed at L3); the RELAXED flag store is
    // then ordered behind all h-stores. NO release -> NO wbl2 tag-walk.
    __syncthreads();
    if (tid == 0)
      __hip_atomic_store(flags + ((size_t)t * 16 + bx) * 16 + dt, 1,
                         __ATOMIC_RELAXED, __HIP_MEMORY_SCOPE_AGENT);
  }
#undef LDSA
#undef LOAD_B
#undef MFMA_BLK
}

// ---------------- phase C: merged projection GEMM ----------------
// rows = 131072 (t*NB+b), cols = 896 packed [Wwp 512 | Wu 288 | pad].
// ct<4: tanh(+bwp)*vp row-reduction -> atomicAdd partials.
// ct>=4: U write, b-major UT[b][t][uc], uc<288.
__global__ __launch_bounds__(256) void proj_gemm(
    const u16* __restrict__ H, const u16* __restrict__ Wp,
    const float* __restrict__ bwp, const float* __restrict__ vp,
    float* __restrict__ apart, u16* __restrict__ UT)
{
  __shared__ __align__(16) u16 As[3][4096];
  __shared__ __align__(16) u16 Bs[3][4096];
  int tid = threadIdx.x, lane = tid & 63, w = tid >> 6;
  int col = lane & 15, quad = lane >> 4;
  size_t r0 = (size_t)blockIdx.y * 128;
  int ct = blockIdx.x;
  const u16* Abase = H + r0 * KSTEP;
  const u16* Bbase = Wp + (size_t)ct * 128 * 512;
  f32x4 acc[4][4] = {};
  stage128(As[0], Abase, KSTEP);      stage128(Bs[0], Bbase, 512);
  stage128(As[1], Abase + 32, KSTEP); stage128(Bs[1], Bbase + 32, 512);
  for (int kk = 0; kk < 16; ++kk) {
    __syncthreads();
    if (kk + 2 < 16) {
      int m = (kk + 2) % 3;
      stage128(As[m], Abase + (kk + 2) * 32, KSTEP);
      stage128(Bs[m], Bbase + (kk + 2) * 32, 512);
    }
    compute_tile(As[kk % 3], Bs[kk % 3], w, col, quad, acc);
  }
  if (ct < 4) {
    float part[4][4] = {};
    #pragma unroll
    for (int nt = 0; nt < 4; ++nt) {
      int oc = ct * 128 + (w & 1) * 64 + nt * 16 + col;
      float bw = bwp[oc], vv = vp[oc];
      #pragma unroll
      for (int mt = 0; mt < 4; ++mt)
        #pragma unroll
        for (int r = 0; r < 4; ++r) part[mt][r] += tanh_(acc[mt][nt][r] + bw) * vv;
    }
    #pragma unroll
    for (int mt = 0; mt < 4; ++mt)
      #pragma unroll
      for (int r = 0; r < 4; ++r) {
        float p = part[mt][r];
        p += __shfl_xor(p, 1); p += __shfl_xor(p, 2);
        p += __shfl_xor(p, 4); p += __shfl_xor(p, 8);
        if (col == 0)
          atomicAdd(&apart[r0 + (w >> 1) * 64 + mt * 16 + quad * 4 + r], p);
      }
  } else {
    #pragma unroll
    for (int nt = 0; nt < 4; ++nt) {
      int uc = (ct - 4) * 128 + (w & 1) * 64 + nt * 16 + col;
      if (uc < UW) {
        #pragma unroll
        for (int mt = 0; mt < 4; ++mt)
          #pragma unroll
          for (int r = 0; r < 4; ++r) {
            size_t row = r0 + (w >> 1) * 64 + mt * 16 + quad * 4 + r;
            int t = (int)(row >> 11), b = (int)(row & 2047);
            UT[((size_t)b * NT + t) * UW + uc] = f2bf(acc[mt][nt][r]);
          }
      }
    }
  }
}

__global__ void finish_aligned(const float* __restrict__ apart,
                               const float* __restrict__ bvp,
                               float* __restrict__ alg)
{
  int i = blockIdx.x * 256 + threadIdx.x;
  if (i < 131072) alg[i] = 64.f * sig(apart[i] + bvp[0]);
}

// ---------------- attention ----------------
__global__ __launch_bounds__(256) void attn_kernel(
    const u16* __restrict__ cEncB, const u16* __restrict__ UT,
    const float* __restrict__ alignedIn, const float* __restrict__ cw,
    const float* __restrict__ bfc,
    float* __restrict__ preds, float* __restrict__ alphas)
{
  __shared__ __align__(16) u16 Ae[64 * 256];
  __shared__ __align__(16) u16 Ue[64 * 256];
  __shared__ float attL[64 * 68];
  __shared__ float s0L[64], hwL[64], alL[64], cwL[64], mL[64], zL[64];
  __shared__ float red[4][64];
  int tid = threadIdx.x, lane = tid & 63, w = tid >> 6;
  int col = lane & 15, quad = lane >> 4;
  int b = blockIdx.x;
  const u16* eb = cEncB + (size_t)b * NS * NE;
  const u16* ub = UT + (size_t)b * NT * UW;
  // stage: 2048 slots each; slot idx holds row r = idx>>5, global chunk g = (idx&31)^(r&7)
  for (int sw = 0; sw < 8; ++sw) {
    int idx = sw * 256 + tid;
    int r = idx >> 5, cs = idx & 31, g = cs ^ (r & 7);
    ld16(&Ae[idx * 8], eb + (size_t)r * NE + g * 8);
    ld16(&Ue[idx * 8], ub + (size_t)r * UW + g * 8);
  }
  if (tid < 64) {
    s0L[tid] = bf2f(ub[tid * UW + 256]);
    hwL[tid] = bf2f(ub[tid * UW + 257]);
    alL[tid] = alignedIn[(size_t)tid * NB + b];
    cwL[tid] = cw[b * NS + tid];
  }
  __syncthreads();
  f32x4 acc[4] = {};
  int rowA = w * 16 + col;
  #pragma unroll
  for (int kk = 0; kk < 8; ++kk) {
    int ga = (kk * 4 + quad);
    bf16x8 a = *(const bf16x8*)&Ae[(rowA * 32 + (ga ^ (rowA & 7))) * 8];
    #pragma unroll
    for (int nt = 0; nt < 4; ++nt) {
      int rowB = nt * 16 + col;
      bf16x8 bb = *(const bf16x8*)&Ue[(rowB * 32 + (ga ^ (rowB & 7))) * 8];
      acc[nt] = MFMA16(a, bb, acc[nt]);
    }
  }
  for (int nt = 0; nt < 4; ++nt) {
    int t = nt * 16 + col;
    #pragma unroll
    for (int r = 0; r < 4; ++r) {
      int s = w * 16 + quad * 4 + r;
      attL[s * 68 + t] = acc[nt][r] + s0L[t];
    }
  }
  __syncthreads();
  int t = tid & 63, qq = tid >> 6;
  float pm = -1e30f;
  for (int s = qq * 16; s < qq * 16 + 16; ++s) pm = fmaxf(pm, attL[s * 68 + t]);
  red[qq][t] = pm;
  __syncthreads();
  if (tid < 64)
    mL[tid] = fmaxf(fmaxf(red[0][tid], red[1][tid]), fmaxf(red[2][tid], red[3][tid]));
  __syncthreads();
  float m = mL[t];
  float ps = 0.f;
  for (int s = qq * 16; s < qq * 16 + 16; ++s) ps += __expf(attL[s * 68 + t] - m);
  red[qq][t] = ps;
  __syncthreads();
  if (tid < 64) zL[tid] = red[0][tid] + red[1][tid] + red[2][tid] + red[3][tid];
  __syncthreads();
  float zinv = 1.f / zL[t];
  float al = alL[t];
  float pp = 0.f;
  float* aout = alphas + (size_t)b * (NT * NS) + t * NS;
  for (int s = qq * 16; s < qq * 16 + 16; ++s) {
    float e = __expf(attL[s * 68 + t] - m) * zinv;
    float ds = (float)s - al;
    float a = e * __expf(-0.5f * ds * ds);
    aout[s] = a;
    pp += a * cwL[s];
  }
  red[qq][t] = pp;
  __syncthreads();
  if (tid < 64)
    preds[(size_t)b * NT + tid] =
        red[0][tid] + red[1][tid] + red[2][tid] + red[3][tid] + hwL[tid] + bfc[0];
}

extern "C" void kernel_launch(void* const* d_in, const int* in_sizes, int n_in,
                              void* d_out, int out_size, void* d_ws, size_t ws_size,
                              hipStream_t stream) {
  const float* cEnc = (const float*)d_in[0];
  const float* cur  = (const float*)d_in[1];
  const float* hist = (const float*)d_in[2];
  const float* WIh  = (const float*)d_in[6];
  const float* bIh  = (const float*)d_in[7];
  const float* WIc  = (const float*)d_in[8];
  const float* bIc  = (const float*)d_in[9];
  const float* Wih  = (const float*)d_in[10];
  const float* Whh  = (const float*)d_in[11];
  const float* bih  = (const float*)d_in[12];
  const float* bhh  = (const float*)d_in[13];
  const float* Wwa  = (const float*)d_in[14];
  const float* bwa  = (const float*)d_in[15];
  const float* Wwp  = (const float*)d_in[16];
  const float* bwp  = (const float*)d_in[17];
  const float* Wvp  = (const float*)d_in[18];
  const float* bvp  = (const float*)d_in[19];
  const float* Wfc  = (const float*)d_in[20];
  const float* bfc  = (const float*)d_in[21];
  float* preds  = (float*)d_out;
  float* alphas = preds + (size_t)NB * NT;

  char* ws = (char*)d_ws;
  size_t off = 0;
  auto alloc = [&](size_t bytes) { void* p = ws + off; off += (bytes + 255) & ~(size_t)255; return p; };
  u16*   XH    = (u16*)  alloc((size_t)65 * SLAB * 2);
  u16*   UT    = (u16*)  alloc((size_t)NB * NT * UW * 2);
  u16*   cEncB = (u16*)  alloc((size_t)NB * NS * NE * 2);
  float* cbuf  = (float*)alloc((size_t)NB * ND * 4);
  float* inp0  = (float*)alloc((size_t)NB * 288 * 4);
  float* cwb   = (float*)alloc((size_t)NB * NS * 4);
  float* alg   = (float*)alloc((size_t)131072 * 4);
  float* apart = (float*)alloc((size_t)131072 * 4);
  u16*   Wc3   = (u16*)  alloc((size_t)2048 * 544 * 2);
  u16*   Wproj = (u16*)  alloc((size_t)896 * 512 * 2);
  float* bsum  = (float*)alloc((size_t)2048 * 4);
  int*   flags = (int*)  alloc((size_t)64 * 16 * 16 * 4);

  static bool lds_attr_set = false;
  if (!lds_attr_set) {
    (void)hipFuncSetAttribute((const void*)lstm_fused,
                              hipFuncAttributeMaxDynamicSharedMemorySize, 139264);
    lds_attr_set = true;
  }

  prep_enc<<<NB, 256, 0, stream>>>(cEnc, Wfc, hist, cur, inp0, cwb, cEncB);
  xfill<<<16640, 256, 0, stream>>>(hist, cur, XH);
  cast_wc3<<<4352, 256, 0, stream>>>(Wih, Whh, Wc3);
  bsum_k<<<8, 256, 0, stream>>>(bih, bhh, bsum);
  cast_wproj<<<1792, 256, 0, stream>>>(Wwp, Wwa, bwa, Wfc, Wproj);
  init_gemm<<<dim3(32, 16), 256, 0, stream>>>(inp0, WIh, WIc, bIh, bIc, XH, cbuf);
  hipMemsetAsync(apart, 0, (size_t)131072 * 4, stream);
  hipMemsetAsync(flags, 0, (size_t)64 * 16 * 16 * 4, stream);
  lstm_fused<<<dim3(16, 16), 256, 139264, stream>>>(XH, Wc3, bsum, cbuf, flags);
  const u16* H = XH + (size_t)SLAB + 32;
  proj_gemm<<<dim3(7, 1024), 256, 0, stream>>>(H, Wproj, bwp, Wvp, apart, UT);
  finish_aligned<<<512, 256, 0, stream>>>(apart, bvp, alg);
  attn_kernel<<<NB, 256, 0, stream>>>(cEncB, UT, alg, cwb, bfc, preds, alphas);
}